// Round 1
// baseline (62.233 us; speedup 1.0000x reference)
//
#include <hip/hip_runtime.h>

#define FH 50
#define FW 50
#define FC 512
#define NROI 1024
#define NPIX (NROI * 49)   // 1024 rois * 7*7 pooled pixels

__device__ __forceinline__ float4 blend4(float4 tl, float4 tr, float4 bl, float4 br,
                                         float w00, float w01, float w10, float w11) {
    float4 r;
    r.x = tl.x * w00 + tr.x * w01 + bl.x * w10 + br.x * w11;
    r.y = tl.y * w00 + tr.y * w01 + bl.y * w10 + br.y * w11;
    r.z = tl.z * w00 + tr.z * w01 + bl.z * w10 + br.z * w11;
    r.w = tl.w * w00 + tr.w * w01 + bl.w * w10 + br.w * w11;
    return r;
}

__device__ __forceinline__ void max4(float4& m, float4 v) {
    m.x = fmaxf(m.x, v.x);
    m.y = fmaxf(m.y, v.y);
    m.z = fmaxf(m.z, v.z);
    m.w = fmaxf(m.w, v.w);
}

__global__ __launch_bounds__(256) void roi_pool_kernel(
    const float* __restrict__ feature,   // (1,50,50,512)
    const float* __restrict__ rois,      // (1024,4) x1,y1,x2,y2
    const int*   __restrict__ img_size,  // (2) H,W
    float*       __restrict__ out)       // (1024,7,7,512)
{
    // one wave per output pixel; lane handles channels lane*4 and lane*4+256
    int wid  = (blockIdx.x * 256 + threadIdx.x) >> 6;
    int lane = threadIdx.x & 63;
    if (wid >= NPIX) return;

    int n   = wid / 49;
    int rem = wid - n * 49;
    int py  = rem / 7;
    int px  = rem - py * 7;

    float ih = (float)img_size[0];
    float iw = (float)img_size[1];
    float4 rv = *reinterpret_cast<const float4*>(rois + (size_t)n * 4);
    float x1 = rv.x / iw, y1 = rv.y / ih, x2 = rv.z / iw, y2 = rv.w / ih;

    const float HM1 = (float)(FH - 1);   // 49
    const float WM1 = (float)(FW - 1);   // 49
    float sy = (y2 - y1) * HM1 / 13.0f;  // (ch-1)=13
    float sx = (x2 - x1) * WM1 / 13.0f;
    float oy = y1 * HM1;
    float ox = x1 * WM1;

    int   ti[2], bi[2], li[2], ri[2];
    float ly[2], lx[2];
    bool  vy[2], vx[2];
#pragma unroll
    for (int d = 0; d < 2; ++d) {
        float in_y = oy + (float)(2 * py + d) * sy;
        float fy = floorf(in_y);
        ly[d] = in_y - fy;
        ti[d] = (int)fminf(fmaxf(fy, 0.0f), HM1);
        bi[d] = (int)fminf(fmaxf(fy + 1.0f, 0.0f), HM1);
        vy[d] = (in_y >= 0.0f) && (in_y <= HM1);

        float in_x = ox + (float)(2 * px + d) * sx;
        float fx = floorf(in_x);
        lx[d] = in_x - fx;
        li[d] = (int)fminf(fmaxf(fx, 0.0f), WM1);
        ri[d] = (int)fminf(fmaxf(fx + 1.0f, 0.0f), WM1);
        vx[d] = (in_x >= 0.0f) && (in_x <= WM1);
    }

    int c0 = lane * 4;
    float4 m0 = make_float4(-3.402823466e+38f, -3.402823466e+38f,
                            -3.402823466e+38f, -3.402823466e+38f);
    float4 m1 = m0;

#pragma unroll
    for (int dy = 0; dy < 2; ++dy) {
        const float* p_t = feature + (size_t)(ti[dy] * FW) * FC;
        const float* p_b = feature + (size_t)(bi[dy] * FW) * FC;
        float lyv = ly[dy];
        float omy = 1.0f - lyv;
#pragma unroll
        for (int dx = 0; dx < 2; ++dx) {
            float lxv = lx[dx];
            float omx = 1.0f - lxv;
            float w00 = omy * omx, w01 = omy * lxv;
            float w10 = lyv * omx, w11 = lyv * lxv;
            bool  v = vy[dy] && vx[dx];

            int ol = li[dx] * FC + c0;
            int orr = ri[dx] * FC + c0;

            float4 tl0 = *reinterpret_cast<const float4*>(p_t + ol);
            float4 tr0 = *reinterpret_cast<const float4*>(p_t + orr);
            float4 bl0 = *reinterpret_cast<const float4*>(p_b + ol);
            float4 br0 = *reinterpret_cast<const float4*>(p_b + orr);
            float4 tl1 = *reinterpret_cast<const float4*>(p_t + ol + 256);
            float4 tr1 = *reinterpret_cast<const float4*>(p_t + orr + 256);
            float4 bl1 = *reinterpret_cast<const float4*>(p_b + ol + 256);
            float4 br1 = *reinterpret_cast<const float4*>(p_b + orr + 256);

            float4 v0 = blend4(tl0, tr0, bl0, br0, w00, w01, w10, w11);
            float4 v1 = blend4(tl1, tr1, bl1, br1, w00, w01, w10, w11);
            if (!v) {
                v0 = make_float4(0.f, 0.f, 0.f, 0.f);
                v1 = make_float4(0.f, 0.f, 0.f, 0.f);
            }
            max4(m0, v0);
            max4(m1, v1);
        }
    }

    float* po = out + (size_t)wid * FC + c0;
    *reinterpret_cast<float4*>(po)       = m0;
    *reinterpret_cast<float4*>(po + 256) = m1;
}

extern "C" void kernel_launch(void* const* d_in, const int* in_sizes, int n_in,
                              void* d_out, int out_size, void* d_ws, size_t ws_size,
                              hipStream_t stream) {
    const float* feature  = (const float*)d_in[0];
    const float* rois     = (const float*)d_in[1];
    const int*   img_size = (const int*)d_in[2];
    float* out = (float*)d_out;

    // NPIX waves, 4 waves (256 threads) per block -> 12544 blocks, no tail
    int blocks = NPIX / 4;
    roi_pool_kernel<<<blocks, 256, 0, stream>>>(feature, rois, img_size, out);
}